// Round 7
// baseline (24.715 us; speedup 1.0000x reference)
//
#include <hip/hip_runtime.h>
#include <float.h>
#include <math.h>

// Problem constants (from reference)
constexpr int B  = 16;
constexpr int VS = 10475;
constexpr int VO = 8192;
constexpr int K  = 64;
constexpr int PS = 1024;
constexpr int PO = 2048;

// Geometry: 256 blocks (1/CU) x 512 threads (8 waves = 2/SIMD).
// Block = (k, 256-query chunk). All 2048 objects of k staged in LDS.
// 16 half-wave jgroups x 128 objects each; each lane owns 8 queries
// (4 packed f32 pairs).
constexpr int BLK  = 512;
constexpr int QPB  = 256;              // queries per block
constexpr int GRID = K * (PS / QPB);   // 256
constexpr int NG   = 16;               // jgroups (half-waves) per block
constexpr int JPG  = PO / NG;          // 128 objects per jgroup
constexpr int QL   = 8;                // queries per lane

typedef float v2f __attribute__((ext_vector_type(2)));
typedef float v4f __attribute__((ext_vector_type(4)));

// ---------------- kernel 1: full min + block partial sum ----------------

__global__ __launch_bounds__(BLK)
void cl_onepass(const float* __restrict__ smplx_v,
                const float* __restrict__ object_v,
                const int*   __restrict__ spi,
                const int*   __restrict__ opi,
                const int*   __restrict__ bidx,
                float*       __restrict__ partial)   // [GRID]
{
    __shared__ v4f    so[PO];        // (x,y,z, 0.5*|o|^2) -> 32 KiB
    __shared__ float4 qld[QPB];      // (x,y,z, |s|^2)     ->  4 KiB
    __shared__ float  red[NG][QPB];  //                    -> 16 KiB
    __shared__ float  wsum[4];

    const int bk  = blockIdx.x;
    const int tid = threadIdx.x;
    const int k   = bk >> 2;
    const int ic  = bk & 3;
    const int b   = bidx[k];

    // ---- gather: this block's 256 queries (waves 0-3) ----
    if (tid < QPB) {
        const int i  = ic * QPB + tid;
        const int si = spi[k * PS + i];
        const float* __restrict__ sv = smplx_v + ((size_t)b * VS + si) * 3;
        const float x = sv[0], y = sv[1], z = sv[2];
        qld[tid] = make_float4(x, y, z, x * x + y * y + z * z);
    }
    // ---- gather: all 2048 objects of this k (all 8 waves) ----
    const float* __restrict__ ov = object_v + (size_t)b * VO * 3;
    #pragma unroll
    for (int r = 0; r < PO / BLK; ++r) {
        const int j  = r * BLK + tid;
        const int oj = opi[k * PO + j];
        const float x = ov[oj * 3 + 0];
        const float y = ov[oj * 3 + 1];
        const float z = ov[oj * 3 + 2];
        so[j] = (v4f){x, y, z, 0.5f * (x * x + y * y + z * z)};
    }
    __syncthreads();

    // ---- setup: lane owns 8 queries as 4 packed pairs ----
    const int g  = tid >> 5;         // jgroup 0..15 (half-wave)
    const int gl = tid & 31;
    const int qb = gl * QL;

    v2f nsx[4], nsy[4], nsz[4], mint[4];
    #pragma unroll
    for (int p = 0; p < 4; ++p) {
        const float4 qa = qld[qb + 2 * p];
        const float4 qc = qld[qb + 2 * p + 1];
        nsx[p] = (v2f){-qa.x, -qc.x};
        nsy[p] = (v2f){-qa.y, -qc.y};
        nsz[p] = (v2f){-qa.z, -qc.z};
        mint[p] = (v2f){FLT_MAX, FLT_MAX};
    }

    // ---- hot loop: min over this jgroup's 128 objects, 2 per iter ----
    // t = 0.5*|o|^2 - s.o for 2 queries per v_pk_fma_f32 (op_sel splats the
    // object components straight out of the (x,y),(z,w) register pairs).
    // Nested fminf fuses to v_min3_f32: 16 inst / (2 obj x 8 queries).
    const v4f* __restrict__ sog = &so[g * JPG];
    #pragma unroll 4
    for (int j = 0; j < JPG; j += 2) {
        const v4f o0 = sog[j];
        const v4f o1 = sog[j + 1];
        const v2f o0xy = __builtin_shufflevector(o0, o0, 0, 1);
        const v2f o0zw = __builtin_shufflevector(o0, o0, 2, 3);
        const v2f o1xy = __builtin_shufflevector(o1, o1, 0, 1);
        const v2f o1zw = __builtin_shufflevector(o1, o1, 2, 3);
        #pragma unroll
        for (int p = 0; p < 4; ++p) {
            v2f t0, t1;
            asm("v_pk_fma_f32 %0, %1, %2, %3 op_sel:[0,0,1] op_sel_hi:[0,1,1]"
                : "=v"(t0) : "v"(o0xy), "v"(nsx[p]), "v"(o0zw));
            asm("v_pk_fma_f32 %0, %1, %2, %0 op_sel:[1,0,0] op_sel_hi:[1,1,1]"
                : "+v"(t0) : "v"(o0xy), "v"(nsy[p]));
            asm("v_pk_fma_f32 %0, %1, %2, %0 op_sel:[0,0,0] op_sel_hi:[0,1,1]"
                : "+v"(t0) : "v"(o0zw), "v"(nsz[p]));
            asm("v_pk_fma_f32 %0, %1, %2, %3 op_sel:[0,0,1] op_sel_hi:[0,1,1]"
                : "=v"(t1) : "v"(o1xy), "v"(nsx[p]), "v"(o1zw));
            asm("v_pk_fma_f32 %0, %1, %2, %0 op_sel:[1,0,0] op_sel_hi:[1,1,1]"
                : "+v"(t1) : "v"(o1xy), "v"(nsy[p]));
            asm("v_pk_fma_f32 %0, %1, %2, %0 op_sel:[0,0,0] op_sel_hi:[0,1,1]"
                : "+v"(t1) : "v"(o1zw), "v"(nsz[p]));
            mint[p].x = fminf(mint[p].x, fminf(t0.x, t1.x));   // -> v_min3_f32
            mint[p].y = fminf(mint[p].y, fminf(t0.y, t1.y));
        }
    }

    // ---- cross-jgroup min via LDS ----
    #pragma unroll
    for (int p = 0; p < 4; ++p) {
        red[g][qb + 2 * p]     = mint[p].x;
        red[g][qb + 2 * p + 1] = mint[p].y;
    }
    __syncthreads();

    // ---- finalize query tid (waves 0-3), wave shuffle-reduce ----
    if (tid < QPB) {
        float m = red[0][tid];
        #pragma unroll
        for (int g2 = 1; g2 < NG; ++g2) m = fminf(m, red[g2][tid]);
        const float s2q = qld[tid].w;
        float v = sqrtf(fmaxf(fmaf(2.0f, m, s2q), 0.0f));
        #pragma unroll
        for (int off = 32; off > 0; off >>= 1)
            v += __shfl_down(v, off, 64);
        if ((tid & 63) == 0) wsum[tid >> 6] = v;
    }
    __syncthreads();
    if (tid == 0) partial[bk] = (wsum[0] + wsum[1]) + (wsum[2] + wsum[3]);
}

// ---------------- kernel 2: final 256 -> 1 reduce (one wave) ----------------

__global__ __launch_bounds__(64)
void cl_final(const float* __restrict__ partial, float* __restrict__ out)
{
    const int t = threadIdx.x;
    const float4 v4 = ((const float4*)partial)[t];   // 64 lanes x 4 = 256
    float v = (v4.x + v4.y) + (v4.z + v4.w);
    #pragma unroll
    for (int off = 32; off > 0; off >>= 1)
        v += __shfl_down(v, off, 64);
    if (t == 0) out[0] = v * (1.0f / (float)(K * PS));
}

// ---------------- launcher ----------------

extern "C" void kernel_launch(void* const* d_in, const int* in_sizes, int n_in,
                              void* d_out, int out_size, void* d_ws, size_t ws_size,
                              hipStream_t stream)
{
    const float* smplx_v       = (const float*)d_in[0];
    const float* object_v      = (const float*)d_in[1];
    const int*   smpl_part_idx = (const int*)d_in[2];
    const int*   obj_part_idx  = (const int*)d_in[3];
    const int*   batch_idx     = (const int*)d_in[4];
    float*       out           = (float*)d_out;

    float* partial = (float*)d_ws;   // GRID floats

    cl_onepass<<<GRID, BLK, 0, stream>>>(
        smplx_v, object_v, smpl_part_idx, obj_part_idx, batch_idx, partial);
    cl_final<<<1, 64, 0, stream>>>(partial, out);
}